// Round 5
// baseline (5101.587 us; speedup 1.0000x reference)
//
#include <hip/hip_runtime.h>

#define B_   512
#define H_   1024
#define OUT_ 512
#define T_   128
#define APAD 72                 // proj_big LDS pad (f16)
#define BUFH (192 * APAD)
#define BH_  ((size_t)B_ * H_)  // elems in one h slab

typedef _Float16 h8  __attribute__((ext_vector_type(8)));
typedef _Float16 h4  __attribute__((ext_vector_type(4)));
typedef float    f32x4 __attribute__((ext_vector_type(4)));

#define MFMA16(a,b,c) __builtin_amdgcn_mfma_f32_16x16x32_f16(a,b,c,0,0,0)

__device__ __forceinline__ float sigf_(float x) {
  return __builtin_amdgcn_rcpf(1.f + __expf(-x));
}
__device__ __forceinline__ float tanhf_(float x) {
  x = fmaxf(fminf(x, 20.f), -20.f);          // avoid inf*0=NaN for |x|>44
  float e = __expf(-2.f * x);
  return (1.f - e) * __builtin_amdgcn_rcpf(1.f + e);
}
__device__ __forceinline__ h8 cvt8_(f32x4 lo, f32x4 hi) {
  h8 r;
#pragma unroll
  for (int e = 0; e < 4; ++e) { r[e] = (_Float16)lo[e]; r[4 + e] = (_Float16)hi[e]; }
  return r;
}

// ---------------------------------------------------------------------------
// setup: Wlin f32->f16, zero h0 slab
// ---------------------------------------------------------------------------
__global__ __launch_bounds__(256) void setup2_kernel(
    const float* __restrict__ Wlin, _Float16* __restrict__ Wlin16,
    _Float16* __restrict__ h0) {
  int idx = blockIdx.x * 256 + threadIdx.x;    // grid 512 -> 131072 threads
  f32x4 v = ((const f32x4*)Wlin)[idx];         // 131072 f32x4 exactly
  h4 o;
#pragma unroll
  for (int r = 0; r < 4; ++r) o[r] = (_Float16)v[r];
  ((h4*)Wlin16)[idx] = o;
  if (idx < 65536) ((f32x4*)h0)[idx] = (f32x4){0.f, 0.f, 0.f, 0.f};
}

// ---------------------------------------------------------------------------
// Poison-robust grid barrier: flags[blk]=gen (gen=step#, never 0xAAAAAAAA),
// block0's 256 threads poll the 256 flags, then release `go`=gen.
// Requires all 256 blocks co-resident: guaranteed (grid=CU count, 128 KiB LDS
// forbids 2 blocks/CU). Device-scope atomics + threadfence for cross-XCD.
// ---------------------------------------------------------------------------
__device__ __forceinline__ void gridbar_(unsigned* flags, unsigned* go, unsigned gen) {
  __syncthreads();                              // drains each wave's stores to L2
  if (threadIdx.x == 0) {
    __threadfence();                            // release: wbl2 -> L3
    __hip_atomic_store(&flags[blockIdx.x], gen, __ATOMIC_RELEASE, __HIP_MEMORY_SCOPE_AGENT);
  }
  if (blockIdx.x == 0) {
    while (__hip_atomic_load(&flags[threadIdx.x], __ATOMIC_ACQUIRE, __HIP_MEMORY_SCOPE_AGENT) != gen)
      __builtin_amdgcn_s_sleep(2);
    __syncthreads();
    if (threadIdx.x == 0)
      __hip_atomic_store(go, gen, __ATOMIC_RELEASE, __HIP_MEMORY_SCOPE_AGENT);
  }
  if (threadIdx.x == 0) {
    while (__hip_atomic_load(go, __ATOMIC_ACQUIRE, __HIP_MEMORY_SCOPE_AGENT) != gen)
      __builtin_amdgcn_s_sleep(4);
    __threadfence();                            // acquire side (safety)
  }
  __syncthreads();
}

// ---------------------------------------------------------------------------
// Persistent LSTM: 256 blocks, one per CU. Block = (m-slab 128 rows, 16 h-cols
// x 4 gates). W_hh tile resident in 128 KiB LDS (XOR-swizzled), x_proj frags
// and c-state in registers across all 128 steps. A-frags direct global->VGPR
// (depth-3 ring). One manual grid barrier per step.
// ---------------------------------------------------------------------------
__global__ __launch_bounds__(256) void lstm_persistent_kernel(
    const float* __restrict__ C,   const float* __restrict__ Whh,
    const float* __restrict__ Wih, const float* __restrict__ bih,
    const float* __restrict__ bhh, _Float16* __restrict__ hs,
    unsigned* __restrict__ flags,  unsigned* __restrict__ go) {
  __shared__ _Float16 Wlds[64 * H_];            // 128 KiB exactly

  const int blk  = blockIdx.x;
  const int slab = blk >> 6;                    // 0..3 (128 rows each)
  const int j0   = (blk & 63) * 16;             // h-col panel
  const int m0   = slab * 128;
  const int tid  = threadIdx.x, w = tid >> 6, lane = tid & 63;
  const int col  = lane & 15;                   // frag col / row-within-16
  const int khi  = lane >> 4;                   // k subchunk *8
  const int xm   = (col & 7) << 4;              // LDS XOR mask (bits 4-6)

  f32x4 acc[4][2];
#pragma unroll
  for (int g = 0; g < 4; ++g) { acc[g][0] = (f32x4){0.f,0.f,0.f,0.f}; acc[g][1] = (f32x4){0.f,0.f,0.f,0.f}; }

  // ---- prologue A: x_proj fragments (C @ Wih^T) straight from f32 global ----
  {
    const float* aC0 = C + (size_t)(m0 + w * 32 + col) * H_ + khi * 8;
    const float* aC1 = aC0 + 16 * H_;
    const float* bW0 = Wih + (size_t)(0 * H_ + j0 + col) * H_ + khi * 8;
    const float* bW1 = Wih + (size_t)(1 * H_ + j0 + col) * H_ + khi * 8;
    const float* bW2 = Wih + (size_t)(2 * H_ + j0 + col) * H_ + khi * 8;
    const float* bW3 = Wih + (size_t)(3 * H_ + j0 + col) * H_ + khi * 8;
#pragma unroll 2
    for (int kt = 0; kt < 16; ++kt) {
#pragma unroll
      for (int s2 = 0; s2 < 2; ++s2) {
        int kb = kt * 64 + s2 * 32;
        h8 af0 = cvt8_(*(const f32x4*)(aC0 + kb), *(const f32x4*)(aC0 + kb + 4));
        h8 af1 = cvt8_(*(const f32x4*)(aC1 + kb), *(const f32x4*)(aC1 + kb + 4));
        h8 bf;
        bf = cvt8_(*(const f32x4*)(bW0 + kb), *(const f32x4*)(bW0 + kb + 4));
        acc[0][0] = MFMA16(af0, bf, acc[0][0]); acc[0][1] = MFMA16(af1, bf, acc[0][1]);
        bf = cvt8_(*(const f32x4*)(bW1 + kb), *(const f32x4*)(bW1 + kb + 4));
        acc[1][0] = MFMA16(af0, bf, acc[1][0]); acc[1][1] = MFMA16(af1, bf, acc[1][1]);
        bf = cvt8_(*(const f32x4*)(bW2 + kb), *(const f32x4*)(bW2 + kb + 4));
        acc[2][0] = MFMA16(af0, bf, acc[2][0]); acc[2][1] = MFMA16(af1, bf, acc[2][1]);
        bf = cvt8_(*(const f32x4*)(bW3 + kb), *(const f32x4*)(bW3 + kb + 4));
        acc[3][0] = MFMA16(af0, bf, acc[3][0]); acc[3][1] = MFMA16(af1, bf, acc[3][1]);
      }
    }
  }
  f32x4 px[4][2];
#pragma unroll
  for (int g = 0; g < 4; ++g) {
    float bs = bih[g * H_ + j0 + col] + bhh[g * H_ + j0 + col];
    px[g][0] = acc[g][0] + bs;
    px[g][1] = acc[g][1] + bs;
  }

  // ---- prologue B: W_hh panel -> LDS, XOR-swizzled (written once) ----
  {
    int rl = tid >> 2, qc = tid & 3;                    // 64 rows, 4 thr/row
    int grow = (rl >> 4) * H_ + j0 + (rl & 15);         // gate*1024 + j
    const float* src = Whh + (size_t)grow * H_;
    int xw = (rl & 7) << 4;
    char* wb = (char*)Wlds + rl * 2048;
#pragma unroll 4
    for (int c2 = 0; c2 < 32; ++c2) {
      int cc = qc * 32 + c2;                            // 16B chunk in row
      h8 v = cvt8_(*(const f32x4*)(src + cc * 8), *(const f32x4*)(src + cc * 8 + 4));
      *(h8*)(wb + ((cc * 16) ^ xw)) = v;
    }
  }
  __syncthreads();

  const int arow0 = m0 + w * 32 + col;
  f32x4 pc[2] = {(f32x4){0.f,0.f,0.f,0.f}, (f32x4){0.f,0.f,0.f,0.f}};
  const char* wbase = (const char*)Wlds + col * 2048;

#pragma unroll 1
  for (int s = 1; s <= T_; ++s) {
    const _Float16* hp  = hs + (size_t)(s - 1) * BH_;
    const _Float16* ap0 = hp + (size_t)arow0 * H_ + khi * 8;
    const _Float16* ap1 = ap0 + 16 * H_;
#pragma unroll
    for (int g = 0; g < 4; ++g) { acc[g][0] = (f32x4){0.f,0.f,0.f,0.f}; acc[g][1] = (f32x4){0.f,0.f,0.f,0.f}; }

    h8 a[4][2][2];                                      // ring [slot][s2][mf]
#define LDA(S, KT) do {                                                        \
      a[S][0][0] = *(const h8*)(ap0 + (KT) * 64);                              \
      a[S][0][1] = *(const h8*)(ap1 + (KT) * 64);                              \
      a[S][1][0] = *(const h8*)(ap0 + (KT) * 64 + 32);                         \
      a[S][1][1] = *(const h8*)(ap1 + (KT) * 64 + 32);                         \
    } while (0)
    LDA(0, 0); LDA(1, 1); LDA(2, 2);
#pragma unroll
    for (int kt = 0; kt < 16; ++kt) {
      if (kt + 3 < 16) LDA((kt + 3) & 3, kt + 3);
#pragma unroll
      for (int s2 = 0; s2 < 2; ++s2) {
        int boff = (kt * 128 + s2 * 64 + khi * 16) ^ xm;
        h8 b0 = *(const h8*)(wbase + 0 * 32768 + boff);
        h8 b1 = *(const h8*)(wbase + 1 * 32768 + boff);
        h8 b2 = *(const h8*)(wbase + 2 * 32768 + boff);
        h8 b3 = *(const h8*)(wbase + 3 * 32768 + boff);
        acc[0][0] = MFMA16(a[kt & 3][s2][0], b0, acc[0][0]);
        acc[0][1] = MFMA16(a[kt & 3][s2][1], b0, acc[0][1]);
        acc[1][0] = MFMA16(a[kt & 3][s2][0], b1, acc[1][0]);
        acc[1][1] = MFMA16(a[kt & 3][s2][1], b1, acc[1][1]);
        acc[2][0] = MFMA16(a[kt & 3][s2][0], b2, acc[2][0]);
        acc[2][1] = MFMA16(a[kt & 3][s2][1], b2, acc[2][1]);
        acc[3][0] = MFMA16(a[kt & 3][s2][0], b3, acc[3][0]);
        acc[3][1] = MFMA16(a[kt & 3][s2][1], b3, acc[3][1]);
      }
    }
#undef LDA

    _Float16* ho = hs + (size_t)s * BH_;
#pragma unroll
    for (int mf = 0; mf < 2; ++mf) {
      f32x4 cn;
#pragma unroll
      for (int r = 0; r < 4; ++r) {
        float iv = sigf_(acc[0][mf][r] + px[0][mf][r]);
        float fv = sigf_(acc[1][mf][r] + px[1][mf][r]);
        float gv = tanhf_(acc[2][mf][r] + px[2][mf][r]);
        float ov = sigf_(acc[3][mf][r] + px[3][mf][r]);
        float cc = fv * pc[mf][r] + iv * gv;
        cn[r] = cc;
        ho[(size_t)(m0 + w * 32 + mf * 16 + khi * 4 + r) * H_ + j0 + col] =
            (_Float16)(ov * tanhf_(cc));
      }
      pc[mf] = cn;
    }
    gridbar_(flags, go, (unsigned)s);
  }
}

// ---------------------------------------------------------------------------
// Batched final projection: out[65536][512] = hs[1..128] @ W_lin^T + b_lin.
// XCD co-location: the 4 n-tiles of one m-slab land on the same XCD.
// ---------------------------------------------------------------------------
__global__ __launch_bounds__(256) void proj_big_kernel(
    const _Float16* __restrict__ h, const _Float16* __restrict__ Wlin16,
    const float* __restrict__ blin, float* __restrict__ outp) {
  __shared__ __align__(16) _Float16 smem[2 * BUFH];
  int x = blockIdx.x & 7, i = blockIdx.x >> 3;
  int mslab = x * 128 + (i >> 2);          // 0..1023, 4 n-tiles share XCD x
  int n0 = (i & 3) * 128;
  size_t m0 = (size_t)mslab * 64;
  int tid = threadIdx.x, w = tid >> 6, lane = tid & 63;
  int fr_row = lane & 15, fr_k = (lane >> 4) * 8;
  int ar = tid >> 2, ac = (tid & 3) * 16;
  int br = tid >> 1, bq = (tid & 1) * 32;
  const _Float16* Arow = h + (m0 + ar) * H_ + ac;
  const _Float16* Brow = Wlin16 + (size_t)(n0 + br) * H_ + bq;
  f32x4 acc[4][2] = {};
  h8 ra0, ra1, rb0, rb1, rb2, rb3;

#define LOADP(K0) do {                                                        \
    const h8* pa_ = (const h8*)(Arow + (K0));                                 \
    ra0 = pa_[0]; ra1 = pa_[1];                                               \
    const h8* pb_ = (const h8*)(Brow + (K0));                                 \
    rb0 = pb_[0]; rb1 = pb_[1]; rb2 = pb_[2]; rb3 = pb_[3];                   \
  } while (0)
#define STOREP(BUF) do {                                                      \
    _Float16* As_ = smem + (BUF) * BUFH;                                      \
    _Float16* Bs_ = As_ + 64 * APAD;                                          \
    *(h8*)&As_[ar * APAD + ac] = ra0;                                         \
    *(h8*)&As_[ar * APAD + ac + 8] = ra1;                                     \
    _Float16* dst_ = &Bs_[br * APAD + bq];                                    \
    *(h8*)&dst_[0] = rb0; *(h8*)&dst_[8] = rb1;                               \
    *(h8*)&dst_[16] = rb2; *(h8*)&dst_[24] = rb3;                             \
  } while (0)
#define COMPUTEP(BUF) do {                                                    \
    const _Float16* As_ = smem + (BUF) * BUFH;                                \
    const _Float16* Bs_ = As_ + 64 * APAD;                                    \
    _Pragma("unroll")                                                         \
    for (int s2 = 0; s2 < 2; ++s2) {                                          \
      int ks = s2 * 32 + fr_k;                                                \
      h8 b0 = *(const h8*)&Bs_[(w * 32 + fr_row) * APAD + ks];                \
      h8 b1 = *(const h8*)&Bs_[(w * 32 + 16 + fr_row) * APAD + ks];           \
      _Pragma("unroll")                                                       \
      for (int mf = 0; mf < 4; ++mf) {                                        \
        h8 a = *(const h8*)&As_[(mf * 16 + fr_row) * APAD + ks];              \
        acc[mf][0] = MFMA16(a, b0, acc[mf][0]);                               \
        acc[mf][1] = MFMA16(a, b1, acc[mf][1]);                               \
      }                                                                       \
    }                                                                         \
  } while (0)

  LOADP(0);
  STOREP(0);
  __syncthreads();
#pragma unroll
  for (int kt = 0; kt < 16; ++kt) {
    if (kt < 15) LOADP((kt + 1) * 64);
    COMPUTEP(kt & 1);
    if (kt < 15) STOREP((kt + 1) & 1);
    __syncthreads();
  }
#undef LOADP
#undef STOREP
#undef COMPUTEP

  float* fr = (float*)smem + w * 2048;
  float bl0 = blin[n0 + w * 32 + fr_row];
  float bl1 = blin[n0 + w * 32 + 16 + fr_row];
#pragma unroll
  for (int mf = 0; mf < 4; ++mf)
#pragma unroll
    for (int r = 0; r < 4; ++r) {
      fr[(mf * 16 + (lane >> 4) * 4 + r) * 32 + fr_row]      = acc[mf][0][r] + bl0;
      fr[(mf * 16 + (lane >> 4) * 4 + r) * 32 + 16 + fr_row] = acc[mf][1][r] + bl1;
    }
  __syncthreads();
#pragma unroll
  for (int p = 0; p < 8; ++p) {
    int row = p * 8 + (lane >> 3), q = (lane & 7) * 4;
    f32x4 v = *(f32x4*)&fr[row * 32 + q];
    *(f32x4*)(outp + (m0 + row) * OUT_ + n0 + w * 32 + q) = v;
  }
}

// ---------------------------------------------------------------------------
extern "C" void kernel_launch(void* const* d_in, const int* in_sizes, int n_in,
                              void* d_out, int out_size, void* d_ws, size_t ws_size,
                              hipStream_t stream) {
  const float* C    = (const float*)d_in[0];
  const float* Wih  = (const float*)d_in[3];
  const float* Whh  = (const float*)d_in[4];
  const float* bih  = (const float*)d_in[5];
  const float* bhh  = (const float*)d_in[6];
  const float* Wlin = (const float*)d_in[7];
  const float* blin = (const float*)d_in[8];
  float* out = (float*)d_out;

  char* ws = (char*)d_ws;
  size_t off = 0;
  auto alloc = [&](size_t bytes) {
    void* p = ws + off;
    off = (off + bytes + 255) & ~(size_t)255;
    return p;
  };
  _Float16* Wlin16 = (_Float16*)alloc((size_t)OUT_ * H_ * 2);
  _Float16* hs     = (_Float16*)alloc((size_t)(T_ + 1) * BH_ * 2);  // [129][B][H]
  unsigned* flags  = (unsigned*)alloc(256 * sizeof(unsigned));
  unsigned* go     = (unsigned*)alloc(256);
  if (off > ws_size) return;   // ~136 MB needed; proven available (r4 ran 163 MB)

  hipLaunchKernelGGL(setup2_kernel, dim3(512), dim3(256), 0, stream,
                     Wlin, Wlin16, hs /* h0 slab */);
  hipLaunchKernelGGL(lstm_persistent_kernel, dim3(256), dim3(256), 0, stream,
                     C, Whh, Wih, bih, bhh, hs, flags, go);
  hipLaunchKernelGGL(proj_big_kernel, dim3((T_ * B_ / 64) * (OUT_ / 128)),
                     dim3(256), 0, stream, hs + BH_, Wlin16, blin, out);
}